// Round 4
// baseline (1085.807 us; speedup 1.0000x reference)
//
#include <hip/hip_runtime.h>
#include <math.h>

#define TOPK 8
#define NE   128
#define BT   64       // tokens per block (pass1)
#define BK   64       // K tile (pass1)
#define XPAD 72       // x_s row stride (floats)
#define WPAD 132      // w_s row stride (floats)
#define MARGIN 4e-5f

// ---------------- Pass 1: fp32 GEMM + sigmoid + top-8 + near-tie bitmask ----------------
__global__ __launch_bounds__(512, 4) void router_pass1(
    const float* __restrict__ x,       // [T, H]
    const float* __restrict__ W,       // [E, H]
    const float* __restrict__ bias,    // [E]
    float* __restrict__ out_w,         // [T, 8]
    float* __restrict__ out_i,         // [T, 8]
    unsigned int* __restrict__ mask,   // [T/32] near-tie bitmask
    int T, int H) {
  __shared__ float x_s[BT * XPAD];     // 18.4 KB
  __shared__ float w_s[BK * WPAD];     // 33.8 KB

  const int tid = threadIdx.x;
  const int t0  = blockIdx.x * BT;
  const int tx  = tid & 15;            // experts {tx*4..+3} and {64+tx*4..+3}
  const int ty  = tid >> 4;            // 0..31 -> tokens ty*2, ty*2+1
  const int xr  = tid >> 3;            // x staging row 0..63
  const int xc  = tid & 7;             // x staging k-quad 0..7
  const int weg = tid >> 4;            // w staging expert group 0..31
  const int wq  = tid & 15;            // w staging k-quad 0..15

  float biasr[8];
#pragma unroll
  for (int j = 0; j < 4; ++j) {
    biasr[j]     = bias[tx * 4 + j];
    biasr[4 + j] = bias[64 + tx * 4 + j];
  }

  float acc[2][8];
#pragma unroll
  for (int i = 0; i < 2; ++i)
#pragma unroll
    for (int j = 0; j < 8; ++j) acc[i][j] = 0.f;

  for (int k0 = 0; k0 < H; k0 += BK) {
    __syncthreads();
    // ---- stage x: [64 tok][64 k] ----
    {
      const float* xp = x + (size_t)(t0 + xr) * H + k0 + xc * 4;
      const float4 v0 = *(const float4*)(xp);
      const float4 v1 = *(const float4*)(xp + 32);
      *(float4*)(x_s + xr * XPAD + xc * 4)      = v0;
      *(float4*)(x_s + xr * XPAD + 32 + xc * 4) = v1;
    }
    // ---- stage W transposed: [64 k][128 e] ----
    {
      const float* wp = W + (size_t)(weg * 4) * H + k0 + wq * 4;
      const float4 r0 = *(const float4*)(wp);
      const float4 r1 = *(const float4*)(wp + H);
      const float4 r2 = *(const float4*)(wp + 2 * (size_t)H);
      const float4 r3 = *(const float4*)(wp + 3 * (size_t)H);
      *(float4*)(w_s + (wq * 4 + 0) * WPAD + weg * 4) = make_float4(r0.x, r1.x, r2.x, r3.x);
      *(float4*)(w_s + (wq * 4 + 1) * WPAD + weg * 4) = make_float4(r0.y, r1.y, r2.y, r3.y);
      *(float4*)(w_s + (wq * 4 + 2) * WPAD + weg * 4) = make_float4(r0.z, r1.z, r2.z, r3.z);
      *(float4*)(w_s + (wq * 4 + 3) * WPAD + weg * 4) = make_float4(r0.w, r1.w, r2.w, r3.w);
    }
    __syncthreads();

#pragma unroll
    for (int k4 = 0; k4 < BK / 4; ++k4) {
      const float4 xv0 = *(const float4*)(x_s + (ty * 2 + 0) * XPAD + k4 * 4);
      const float4 xv1 = *(const float4*)(x_s + (ty * 2 + 1) * XPAD + k4 * 4);
#pragma unroll
      for (int kk = 0; kk < 4; ++kk) {
        // lo experts at columns 0..63, hi experts at columns 64..127 (floats)
        const float4 wlo = *(const float4*)(w_s + (k4 * 4 + kk) * WPAD + tx * 4);
        const float4 whi = *(const float4*)(w_s + (k4 * 4 + kk) * WPAD + 64 + tx * 4);
        const float xs0 = ((const float*)&xv0)[kk];
        const float xs1 = ((const float*)&xv1)[kk];
        acc[0][0] = fmaf(xs0, wlo.x, acc[0][0]);
        acc[0][1] = fmaf(xs0, wlo.y, acc[0][1]);
        acc[0][2] = fmaf(xs0, wlo.z, acc[0][2]);
        acc[0][3] = fmaf(xs0, wlo.w, acc[0][3]);
        acc[0][4] = fmaf(xs0, whi.x, acc[0][4]);
        acc[0][5] = fmaf(xs0, whi.y, acc[0][5]);
        acc[0][6] = fmaf(xs0, whi.z, acc[0][6]);
        acc[0][7] = fmaf(xs0, whi.w, acc[0][7]);
        acc[1][0] = fmaf(xs1, wlo.x, acc[1][0]);
        acc[1][1] = fmaf(xs1, wlo.y, acc[1][1]);
        acc[1][2] = fmaf(xs1, wlo.z, acc[1][2]);
        acc[1][3] = fmaf(xs1, wlo.w, acc[1][3]);
        acc[1][4] = fmaf(xs1, whi.x, acc[1][4]);
        acc[1][5] = fmaf(xs1, whi.y, acc[1][5]);
        acc[1][6] = fmaf(xs1, whi.z, acc[1][6]);
        acc[1][7] = fmaf(xs1, whi.w, acc[1][7]);
      }
    }
  }

  // ---- epilogue: sigmoid, top-8 across 16-lane groups, flag near-ties ----
  const int lane  = tid & 63;
  const int gbase = lane & 48;

#pragma unroll
  for (int i = 0; i < 2; ++i) {
    float sc[8], bal[8];
#pragma unroll
    for (int j = 0; j < 8; ++j) {
      const float s = 1.f / (1.f + expf(-acc[i][j]));
      sc[j]  = s;
      bal[j] = s + biasr[j];
    }

    float myw[TOPK];
    int   myid[TOPK];
    float prev = 0.f;
    int   flagged = 0;
#pragma unroll
    for (int r = 0; r < TOPK + 1; ++r) {
      // local argmax (j ascending maps to expert index ascending; strict > keeps lowest)
      float bv = bal[0];
      int   bi = tx * 4;
#pragma unroll
      for (int j = 1; j < 8; ++j) {
        const int ej = (j < 4) ? (tx * 4 + j) : (64 + tx * 4 + (j - 4));
        if (bal[j] > bv) { bv = bal[j]; bi = ej; }
      }
#pragma unroll
      for (int m = 1; m <= 8; m <<= 1) {
        const float ov = __shfl_xor(bv, m);
        const int   oi = __shfl_xor(bi, m);
        if (ov > bv || (ov == bv && oi < bi)) { bv = ov; bi = oi; }
      }
      if (r > 0 && (prev - bv) < MARGIN) flagged = 1;
      prev = bv;
      if (r < TOPK) {
        const int ls = (bi < 64) ? (bi >> 2) : ((bi - 64) >> 2);
        const int jt = (bi < 64) ? (bi & 3) : (4 + ((bi - 64) & 3));
        const float a0 = (jt & 1) ? sc[1] : sc[0];
        const float a1 = (jt & 1) ? sc[3] : sc[2];
        const float a2 = (jt & 1) ? sc[5] : sc[4];
        const float a3 = (jt & 1) ? sc[7] : sc[6];
        const float b0 = (jt & 2) ? a1 : a0;
        const float b1 = (jt & 2) ? a3 : a2;
        const float sv = (jt & 4) ? b1 : b0;
        const float sw = __shfl(sv, gbase | ls);
        myw[r]  = sw;
        myid[r] = bi;
#pragma unroll
        for (int j = 0; j < 8; ++j)
          if (tx == ls && j == jt) bal[j] = -INFINITY;
      }
    }

    if (tx == 0) {
      float den = 0.f;
#pragma unroll
      for (int r = 0; r < TOPK; ++r) den += fabsf(myw[r]);
      den = fmaxf(den, 1e-12f);
      const int t = t0 + ty * 2 + i;
      float4* wo = (float4*)(out_w + (size_t)t * TOPK);
      float4* io = (float4*)(out_i + (size_t)t * TOPK);
      wo[0] = make_float4(myw[0] / den, myw[1] / den, myw[2] / den, myw[3] / den);
      wo[1] = make_float4(myw[4] / den, myw[5] / den, myw[6] / den, myw[7] / den);
      io[0] = make_float4((float)myid[0], (float)myid[1], (float)myid[2], (float)myid[3]);
      io[1] = make_float4((float)myid[4], (float)myid[5], (float)myid[6], (float)myid[7]);
      if (flagged) atomicOr(&mask[t >> 5], 1u << (t & 31));
    }
  }
}

// ---------------- Pass 2: fp64 recompute of flagged tokens ----------------
// Fixed grid: block b owns tokens [b*64, b*64+64) = mask words 2b, 2b+1.
// 256 threads = 128 experts x 2 K-halves; one token at a time.
__global__ __launch_bounds__(256) void router_pass2(
    const float* __restrict__ x, const float* __restrict__ W,
    const float* __restrict__ bias,
    float* __restrict__ out_w, float* __restrict__ out_i,
    const unsigned int* __restrict__ mask, int H) {
  __shared__ float  xs[4096];          // 16 KB (H == 4096)
  __shared__ double red[NE];           // 1 KB

  const int tid = threadIdx.x;
  const int e   = tid & 127;
  const int h   = tid >> 7;            // K-half

  const unsigned int m0 = mask[blockIdx.x * 2];
  const unsigned int m1 = mask[blockIdx.x * 2 + 1];
  unsigned long long mm = ((unsigned long long)m1 << 32) | (unsigned long long)m0;
  if (mm == 0ull) return;

  while (mm) {
    const int bitpos = __ffsll((long long)mm) - 1;
    mm &= mm - 1ull;
    const int t = blockIdx.x * 64 + bitpos;

    __syncthreads();                   // protect xs/red reuse across iterations
    {
      const float* xp = x + (size_t)t * H;
#pragma unroll
      for (int c = 0; c < 4; ++c) {
        const int fi = (c * 256 + tid) * 4;
        *(float4*)(xs + fi) = *(const float4*)(xp + fi);
      }
    }
    __syncthreads();

    double a = 0.0;
    {
      const float* wp = W + (size_t)e * H + h * 2048;
      const float* xb = xs + h * 2048;
      for (int kk = 0; kk < 2048; kk += 4) {
        const float4 wv = *(const float4*)(wp + kk);
        a = fma((double)xb[kk + 0], (double)wv.x, a);
        a = fma((double)xb[kk + 1], (double)wv.y, a);
        a = fma((double)xb[kk + 2], (double)wv.z, a);
        a = fma((double)xb[kk + 3], (double)wv.w, a);
      }
    }

    if (h == 1) red[e] = a;
    __syncthreads();
    if (h == 0) {
      const double z = a + red[e];
      red[e] = 1.0 / (1.0 + exp(-z));
    }
    __syncthreads();

    if (tid < 64) {
      const int l = tid;
      const double s0 = red[l];
      const double s1 = red[64 + l];
      double g0 = s0 + (double)bias[l];
      double g1 = s1 + (double)bias[64 + l];
      double myw[TOPK]; int myid[TOPK];
#pragma unroll
      for (int r = 0; r < TOPK; ++r) {
        double bv; int bi;
        if (g1 > g0) { bv = g1; bi = 64 + l; } else { bv = g0; bi = l; }
#pragma unroll
        for (int m = 1; m <= 32; m <<= 1) {
          const double ov = __shfl_xor(bv, m);
          const int    oi = __shfl_xor(bi, m);
          if (ov > bv || (ov == bv && oi < bi)) { bv = ov; bi = oi; }
        }
        const int ls   = bi & 63;
        const int slot = bi >> 6;
        const double sv = slot ? s1 : s0;
        const double sw = __shfl(sv, ls);
        myw[r]  = sw;
        myid[r] = bi;
        if (l == ls) { if (slot) g1 = -INFINITY; else g0 = -INFINITY; }
      }
      if (l == 0) {
        double den = 0.0;
#pragma unroll
        for (int r = 0; r < TOPK; ++r) den += fabs(myw[r]);
        den = fmax(den, 1e-12);
#pragma unroll
        for (int r = 0; r < TOPK; ++r) {
          out_w[(size_t)t * TOPK + r] = (float)(myw[r] / den);
          out_i[(size_t)t * TOPK + r] = (float)myid[r];
        }
      }
    }
  }
}

extern "C" void kernel_launch(void* const* d_in, const int* in_sizes, int n_in,
                              void* d_out, int out_size, void* d_ws, size_t ws_size,
                              hipStream_t stream) {
  const float* x    = (const float*)d_in[0];
  const float* W    = (const float*)d_in[1];
  const float* bias = (const float*)d_in[2];
  const int E = in_sizes[2];            // 128
  const int H = in_sizes[1] / E;        // 4096
  const int T = in_sizes[0] / H;        // 32768
  (void)E; (void)n_in; (void)ws_size; (void)out_size;

  float* out_w = (float*)d_out;
  float* out_i = out_w + (size_t)T * TOPK;

  unsigned int* mask = (unsigned int*)d_ws;
  const size_t mask_bytes = ((size_t)T + 31) / 32 * 4;   // 4 KB at T=32768

  hipMemsetAsync(d_ws, 0, mask_bytes, stream);
  router_pass1<<<dim3(T / BT), dim3(512), 0, stream>>>(x, W, bias, out_w, out_i, mask, T, H);
  router_pass2<<<dim3(T / BT), dim3(256), 0, stream>>>(x, W, bias, out_w, out_i, mask, H);
}

// Round 5
// 750.973 us; speedup vs baseline: 1.4459x; 1.4459x over previous
//
#include <hip/hip_runtime.h>
#include <math.h>

#define TOPK 8
#define NE   128
#define BT   64       // tokens per block (pass1)
#define BK   64       // K tile (pass1)
#define XPAD 72       // x_s row stride (floats)
#define WPAD 132      // w_s row stride (floats)
#define MARGIN 4e-5f

// ---------------- Pass 1: fp32 GEMM + sigmoid + top-8 + near-tie bitmask ----------------
__global__ __launch_bounds__(512, 4) void router_pass1(
    const float* __restrict__ x,       // [T, H]
    const float* __restrict__ W,       // [E, H]
    const float* __restrict__ bias,    // [E]
    float* __restrict__ out_w,         // [T, 8]
    float* __restrict__ out_i,         // [T, 8]
    unsigned int* __restrict__ mask,   // [T/32] near-tie bitmask
    int T, int H) {
  __shared__ float x_s[BT * XPAD];     // 18.4 KB
  __shared__ float w_s[BK * WPAD];     // 33.8 KB

  const int tid = threadIdx.x;
  const int t0  = blockIdx.x * BT;
  const int tx  = tid & 15;            // experts {tx*4..+3} and {64+tx*4..+3}
  const int ty  = tid >> 4;            // 0..31 -> tokens ty*2, ty*2+1
  const int xr  = tid >> 3;            // x staging row 0..63
  const int xc  = tid & 7;             // x staging k-quad 0..7
  const int weg = tid >> 4;            // w staging expert group 0..31
  const int wq  = tid & 15;            // w staging k-quad 0..15

  float biasr[8];
#pragma unroll
  for (int j = 0; j < 4; ++j) {
    biasr[j]     = bias[tx * 4 + j];
    biasr[4 + j] = bias[64 + tx * 4 + j];
  }

  float acc[2][8];
#pragma unroll
  for (int i = 0; i < 2; ++i)
#pragma unroll
    for (int j = 0; j < 8; ++j) acc[i][j] = 0.f;

  const float* xptr = x + (size_t)(t0 + xr) * H + xc * 4;
  const float* wptr = W + (size_t)(weg * 4) * H + wq * 4;

  // ---- prologue: prefetch tile 0 into registers ----
  float4 gx0 = *(const float4*)(xptr);
  float4 gx1 = *(const float4*)(xptr + 32);
  float4 gw0 = *(const float4*)(wptr);
  float4 gw1 = *(const float4*)(wptr + H);
  float4 gw2 = *(const float4*)(wptr + 2 * (size_t)H);
  float4 gw3 = *(const float4*)(wptr + 3 * (size_t)H);

  for (int k0 = 0; k0 < H; k0 += BK) {
    __syncthreads();                   // previous tile's LDS reads done
    // ---- write staged registers to LDS ----
    *(float4*)(x_s + xr * XPAD + xc * 4)      = gx0;
    *(float4*)(x_s + xr * XPAD + 32 + xc * 4) = gx1;
    *(float4*)(w_s + (wq * 4 + 0) * WPAD + weg * 4) = make_float4(gw0.x, gw1.x, gw2.x, gw3.x);
    *(float4*)(w_s + (wq * 4 + 1) * WPAD + weg * 4) = make_float4(gw0.y, gw1.y, gw2.y, gw3.y);
    *(float4*)(w_s + (wq * 4 + 2) * WPAD + weg * 4) = make_float4(gw0.z, gw1.z, gw2.z, gw3.z);
    *(float4*)(w_s + (wq * 4 + 3) * WPAD + weg * 4) = make_float4(gw0.w, gw1.w, gw2.w, gw3.w);
    __syncthreads();

    // ---- issue next tile's global loads (latency hides under compute) ----
    if (k0 + BK < H) {
      const float* xp2 = xptr + k0 + BK;
      const float* wp2 = wptr + k0 + BK;
      gx0 = *(const float4*)(xp2);
      gx1 = *(const float4*)(xp2 + 32);
      gw0 = *(const float4*)(wp2);
      gw1 = *(const float4*)(wp2 + H);
      gw2 = *(const float4*)(wp2 + 2 * (size_t)H);
      gw3 = *(const float4*)(wp2 + 3 * (size_t)H);
    }

    // ---- compute current tile from LDS ----
#pragma unroll
    for (int k4 = 0; k4 < BK / 4; ++k4) {
      const float4 xv0 = *(const float4*)(x_s + (ty * 2 + 0) * XPAD + k4 * 4);
      const float4 xv1 = *(const float4*)(x_s + (ty * 2 + 1) * XPAD + k4 * 4);
#pragma unroll
      for (int kk = 0; kk < 4; ++kk) {
        const float4 wlo = *(const float4*)(w_s + (k4 * 4 + kk) * WPAD + tx * 4);
        const float4 whi = *(const float4*)(w_s + (k4 * 4 + kk) * WPAD + 64 + tx * 4);
        const float xs0 = ((const float*)&xv0)[kk];
        const float xs1 = ((const float*)&xv1)[kk];
        acc[0][0] = fmaf(xs0, wlo.x, acc[0][0]);
        acc[0][1] = fmaf(xs0, wlo.y, acc[0][1]);
        acc[0][2] = fmaf(xs0, wlo.z, acc[0][2]);
        acc[0][3] = fmaf(xs0, wlo.w, acc[0][3]);
        acc[0][4] = fmaf(xs0, whi.x, acc[0][4]);
        acc[0][5] = fmaf(xs0, whi.y, acc[0][5]);
        acc[0][6] = fmaf(xs0, whi.z, acc[0][6]);
        acc[0][7] = fmaf(xs0, whi.w, acc[0][7]);
        acc[1][0] = fmaf(xs1, wlo.x, acc[1][0]);
        acc[1][1] = fmaf(xs1, wlo.y, acc[1][1]);
        acc[1][2] = fmaf(xs1, wlo.z, acc[1][2]);
        acc[1][3] = fmaf(xs1, wlo.w, acc[1][3]);
        acc[1][4] = fmaf(xs1, whi.x, acc[1][4]);
        acc[1][5] = fmaf(xs1, whi.y, acc[1][5]);
        acc[1][6] = fmaf(xs1, whi.z, acc[1][6]);
        acc[1][7] = fmaf(xs1, whi.w, acc[1][7]);
      }
    }
  }

  // ---- epilogue: sigmoid, top-8 across 16-lane groups, flag near-ties ----
  const int lane  = tid & 63;
  const int gbase = lane & 48;

#pragma unroll
  for (int i = 0; i < 2; ++i) {
    float sc[8], bal[8];
#pragma unroll
    for (int j = 0; j < 8; ++j) {
      const float s = 1.f / (1.f + expf(-acc[i][j]));
      sc[j]  = s;
      bal[j] = s + biasr[j];
    }

    float myw[TOPK];
    int   myid[TOPK];
    float prev = 0.f;
    int   flagged = 0;
#pragma unroll
    for (int r = 0; r < TOPK + 1; ++r) {
      float bv = bal[0];
      int   bi = tx * 4;
#pragma unroll
      for (int j = 1; j < 8; ++j) {
        const int ej = (j < 4) ? (tx * 4 + j) : (64 + tx * 4 + (j - 4));
        if (bal[j] > bv) { bv = bal[j]; bi = ej; }
      }
#pragma unroll
      for (int m = 1; m <= 8; m <<= 1) {
        const float ov = __shfl_xor(bv, m);
        const int   oi = __shfl_xor(bi, m);
        if (ov > bv || (ov == bv && oi < bi)) { bv = ov; bi = oi; }
      }
      if (r > 0 && (prev - bv) < MARGIN) flagged = 1;
      prev = bv;
      if (r < TOPK) {
        const int ls = (bi < 64) ? (bi >> 2) : ((bi - 64) >> 2);
        const int jt = (bi < 64) ? (bi & 3) : (4 + ((bi - 64) & 3));
        const float a0 = (jt & 1) ? sc[1] : sc[0];
        const float a1 = (jt & 1) ? sc[3] : sc[2];
        const float a2 = (jt & 1) ? sc[5] : sc[4];
        const float a3 = (jt & 1) ? sc[7] : sc[6];
        const float b0 = (jt & 2) ? a1 : a0;
        const float b1 = (jt & 2) ? a3 : a2;
        const float sv = (jt & 4) ? b1 : b0;
        const float sw = __shfl(sv, gbase | ls);
        myw[r]  = sw;
        myid[r] = bi;
#pragma unroll
        for (int j = 0; j < 8; ++j)
          if (tx == ls && j == jt) bal[j] = -INFINITY;
      }
    }

    if (tx == 0) {
      float den = 0.f;
#pragma unroll
      for (int r = 0; r < TOPK; ++r) den += fabsf(myw[r]);
      den = fmaxf(den, 1e-12f);
      const int t = t0 + ty * 2 + i;
      float4* wo = (float4*)(out_w + (size_t)t * TOPK);
      float4* io = (float4*)(out_i + (size_t)t * TOPK);
      wo[0] = make_float4(myw[0] / den, myw[1] / den, myw[2] / den, myw[3] / den);
      wo[1] = make_float4(myw[4] / den, myw[5] / den, myw[6] / den, myw[7] / den);
      io[0] = make_float4((float)myid[0], (float)myid[1], (float)myid[2], (float)myid[3]);
      io[1] = make_float4((float)myid[4], (float)myid[5], (float)myid[6], (float)myid[7]);
      if (flagged) atomicOr(&mask[t >> 5], 1u << (t & 31));
    }
  }
}

// ---------------- Compaction: bitmask -> ordered token list (deterministic) ----------------
__global__ __launch_bounds__(1024) void router_compact(
    const unsigned int* __restrict__ mask, int* __restrict__ cnt,
    int* __restrict__ flags, int nwords) {
  __shared__ int wsum[17];
  const int tid = threadIdx.x;
  unsigned int w = (tid < nwords) ? mask[tid] : 0u;
  const int c = __popc(w);
  const int lane = tid & 63;
  const int wv   = tid >> 6;
  int inc = c;
#pragma unroll
  for (int m = 1; m < 64; m <<= 1) {
    const int v = __shfl_up(inc, m);
    if (lane >= m) inc += v;
  }
  if (lane == 63) wsum[wv + 1] = inc;
  __syncthreads();
  if (tid == 0) {
    wsum[0] = 0;
    for (int i = 1; i <= 16; ++i) wsum[i] += wsum[i - 1];
    cnt[0] = wsum[16];
  }
  __syncthreads();
  int off = wsum[wv] + inc - c;
  while (w) {
    const int b = __ffs(w) - 1;
    w &= w - 1u;
    flags[off++] = tid * 32 + b;
  }
}

// ---------------- Pass 2: fp64 recompute, one token per block (grid-stride) ----------------
__global__ __launch_bounds__(256) void router_pass2(
    const float* __restrict__ x, const float* __restrict__ W,
    const float* __restrict__ bias,
    float* __restrict__ out_w, float* __restrict__ out_i,
    const int* __restrict__ cnt, const int* __restrict__ flags, int H) {
  __shared__ float  xs[4096];          // 16 KB (H == 4096)
  __shared__ double red[NE];

  const int tid = threadIdx.x;
  const int e   = tid & 127;
  const int h   = tid >> 7;            // K-half
  const int count = cnt[0];

  for (int i = blockIdx.x; i < count; i += gridDim.x) {
    const int t = flags[i];

    __syncthreads();                   // protect xs/red reuse across iterations
    {
      const float* xp = x + (size_t)t * H;
#pragma unroll
      for (int c = 0; c < 4; ++c) {
        const int fi = (c * 256 + tid) * 4;
        *(float4*)(xs + fi) = *(const float4*)(xp + fi);
      }
    }
    __syncthreads();

    double a0 = 0.0, a1 = 0.0, a2 = 0.0, a3 = 0.0;
    {
      const float* wp = W + (size_t)e * H + h * 2048;
      const float* xb = xs + h * 2048;
      for (int kk = 0; kk < 2048; kk += 4) {
        const float4 wv = *(const float4*)(wp + kk);
        a0 = fma((double)xb[kk + 0], (double)wv.x, a0);
        a1 = fma((double)xb[kk + 1], (double)wv.y, a1);
        a2 = fma((double)xb[kk + 2], (double)wv.z, a2);
        a3 = fma((double)xb[kk + 3], (double)wv.w, a3);
      }
    }
    const double a = (a0 + a1) + (a2 + a3);

    if (h == 1) red[e] = a;
    __syncthreads();
    if (h == 0) red[e] = 1.0 / (1.0 + exp(-(a + red[e])));
    __syncthreads();

    if (tid < 64) {
      const int l = tid;
      const double s0 = red[l];
      const double s1 = red[64 + l];
      double g0 = s0 + (double)bias[l];
      double g1 = s1 + (double)bias[64 + l];
      double myw[TOPK]; int myid[TOPK];
#pragma unroll
      for (int r = 0; r < TOPK; ++r) {
        double bv; int bi;
        if (g1 > g0) { bv = g1; bi = 64 + l; } else { bv = g0; bi = l; }
#pragma unroll
        for (int m = 1; m <= 32; m <<= 1) {
          const double ov = __shfl_xor(bv, m);
          const int    oi = __shfl_xor(bi, m);
          if (ov > bv || (ov == bv && oi < bi)) { bv = ov; bi = oi; }
        }
        const int ls   = bi & 63;
        const int slot = bi >> 6;
        const double sv = slot ? s1 : s0;
        const double sw = __shfl(sv, ls);
        myw[r]  = sw;
        myid[r] = bi;
        if (l == ls) { if (slot) g1 = -INFINITY; else g0 = -INFINITY; }
      }
      if (l == 0) {
        double den = 0.0;
#pragma unroll
        for (int r = 0; r < TOPK; ++r) den += fabs(myw[r]);
        den = fmax(den, 1e-12);
#pragma unroll
        for (int r = 0; r < TOPK; ++r) {
          out_w[(size_t)t * TOPK + r] = (float)(myw[r] / den);
          out_i[(size_t)t * TOPK + r] = (float)myid[r];
        }
      }
    }
  }
}

extern "C" void kernel_launch(void* const* d_in, const int* in_sizes, int n_in,
                              void* d_out, int out_size, void* d_ws, size_t ws_size,
                              hipStream_t stream) {
  const float* x    = (const float*)d_in[0];
  const float* W    = (const float*)d_in[1];
  const float* bias = (const float*)d_in[2];
  const int E = in_sizes[2];            // 128
  const int H = in_sizes[1] / E;        // 4096
  const int T = in_sizes[0] / H;        // 32768
  (void)E; (void)n_in; (void)ws_size; (void)out_size;

  float* out_w = (float*)d_out;
  float* out_i = out_w + (size_t)T * TOPK;

  const int nwords = (T + 31) / 32;     // 1024
  unsigned int* mask = (unsigned int*)d_ws;              // 4 KB
  int* cnt   = (int*)d_ws + nwords;                      // 1 int (pad to 16B)
  int* flags = (int*)d_ws + nwords + 4;                  // up to T ints

  hipMemsetAsync(d_ws, 0, (size_t)(nwords + 4) * 4, stream);
  router_pass1<<<dim3(T / BT), dim3(512), 0, stream>>>(x, W, bias, out_w, out_i, mask, T, H);
  router_compact<<<dim3(1), dim3(1024), 0, stream>>>(mask, cnt, flags, nwords);
  router_pass2<<<dim3(2048), dim3(256), 0, stream>>>(x, W, bias, out_w, out_i, cnt, flags, H);
}

// Round 6
// 647.193 us; speedup vs baseline: 1.6777x; 1.1604x over previous
//
#include <hip/hip_runtime.h>
#include <math.h>

#define TOPK 8
#define NE   128
#define BT   64       // tokens per block (pass1)
#define BK   64       // K tile (pass1)
#define XPAD 66       // x_s row stride (floats): 2*r mod 32 spreads 4 ty-groups -> conflict-free reads
#define WPAD 132      // w_s row stride (floats)
#define MARGIN 4e-5f

// ---------------- Pass 1: fp32 GEMM + sigmoid + top-8 + near-tie bitmask ----------------
// 256 threads; micro-tile 4 tokens x 8 experts per thread.
__global__ __launch_bounds__(256, 2) void router_pass1(
    const float* __restrict__ x,       // [T, H]
    const float* __restrict__ W,       // [E, H]
    const float* __restrict__ bias,    // [E]
    float* __restrict__ out_w,         // [T, 8]
    float* __restrict__ out_i,         // [T, 8]
    unsigned int* __restrict__ mask,   // [T/32] near-tie bitmask
    int T, int H) {
  __shared__ float x_s[BT * XPAD];     // 16.9 KB
  __shared__ float w_s[BK * WPAD];     // 33.8 KB

  const int tid = threadIdx.x;
  const int t0  = blockIdx.x * BT;
  const int tx  = tid & 15;            // experts {tx*4..+3} and {64+tx*4..+3}
  const int ty  = tid >> 4;            // 0..15 -> tokens ty*4..ty*4+3
  const int xr  = tid >> 2;            // x staging row 0..63
  const int xc  = tid & 3;             // x staging sub-col
  const int weg = tid >> 3;            // w staging expert group 0..31 (4 experts)
  const int wq  = tid & 7;             // w staging k-quad (two: wq*4 and 32+wq*4)

  float biasr[8];
#pragma unroll
  for (int j = 0; j < 4; ++j) {
    biasr[j]     = bias[tx * 4 + j];
    biasr[4 + j] = bias[64 + tx * 4 + j];
  }

  float acc[4][8];
#pragma unroll
  for (int i = 0; i < 4; ++i)
#pragma unroll
    for (int j = 0; j < 8; ++j) acc[i][j] = 0.f;

  const float* xbase = x + (size_t)(t0 + xr) * H;
  const float* wbase = W + (size_t)(weg * 4) * H;

  float4 gx[4];        // x stage: 4 float4 (row xr, cols j*16 + xc*4)
  float4 gw[4][2];     // w stage: expert e=0..3, half h2=0..1

  // ---- prologue: prefetch tile 0 ----
#pragma unroll
  for (int j = 0; j < 4; ++j)
    gx[j] = *(const float4*)(xbase + j * 16 + xc * 4);
#pragma unroll
  for (int e = 0; e < 4; ++e)
#pragma unroll
    for (int h2 = 0; h2 < 2; ++h2)
      gw[e][h2] = *(const float4*)(wbase + (size_t)e * H + h2 * 32 + wq * 4);

  for (int k0 = 0; k0 < H; k0 += BK) {
    __syncthreads();                   // previous tile's LDS reads done
    // ---- write staged registers to LDS ----
#pragma unroll
    for (int j = 0; j < 4; ++j)
      *(float4*)(x_s + xr * XPAD + j * 16 + xc * 4) = gx[j];
#pragma unroll
    for (int h2 = 0; h2 < 2; ++h2)
#pragma unroll
      for (int j = 0; j < 4; ++j)
        *(float4*)(w_s + (h2 * 32 + wq * 4 + j) * WPAD + weg * 4) =
            make_float4(((const float*)&gw[0][h2])[j], ((const float*)&gw[1][h2])[j],
                        ((const float*)&gw[2][h2])[j], ((const float*)&gw[3][h2])[j]);
    __syncthreads();

    // ---- issue next tile's global loads (hide under 4096-cy compute) ----
    if (k0 + BK < H) {
      const float* xp2 = xbase + k0 + BK;
      const float* wp2 = wbase + k0 + BK;
#pragma unroll
      for (int j = 0; j < 4; ++j)
        gx[j] = *(const float4*)(xp2 + j * 16 + xc * 4);
#pragma unroll
      for (int e = 0; e < 4; ++e)
#pragma unroll
        for (int h2 = 0; h2 < 2; ++h2)
          gw[e][h2] = *(const float4*)(wp2 + (size_t)e * H + h2 * 32 + wq * 4);
    }

    // ---- compute current tile from LDS ----
#pragma unroll
    for (int k4 = 0; k4 < BK / 4; ++k4) {
      float4 xv[4];
#pragma unroll
      for (int i = 0; i < 4; ++i)
        xv[i] = *(const float4*)(x_s + (ty * 4 + i) * XPAD + k4 * 4);
#pragma unroll
      for (int kk = 0; kk < 4; ++kk) {
        const float4 wlo = *(const float4*)(w_s + (k4 * 4 + kk) * WPAD + tx * 4);
        const float4 whi = *(const float4*)(w_s + (k4 * 4 + kk) * WPAD + 64 + tx * 4);
#pragma unroll
        for (int i = 0; i < 4; ++i) {
          const float xs0 = ((const float*)&xv[i])[kk];
          acc[i][0] = fmaf(xs0, wlo.x, acc[i][0]);
          acc[i][1] = fmaf(xs0, wlo.y, acc[i][1]);
          acc[i][2] = fmaf(xs0, wlo.z, acc[i][2]);
          acc[i][3] = fmaf(xs0, wlo.w, acc[i][3]);
          acc[i][4] = fmaf(xs0, whi.x, acc[i][4]);
          acc[i][5] = fmaf(xs0, whi.y, acc[i][5]);
          acc[i][6] = fmaf(xs0, whi.z, acc[i][6]);
          acc[i][7] = fmaf(xs0, whi.w, acc[i][7]);
        }
      }
    }
  }

  // ---- epilogue: sigmoid, top-8 across 16-lane groups, flag near-ties ----
  const int lane  = tid & 63;
  const int gbase = lane & 48;

#pragma unroll
  for (int i = 0; i < 4; ++i) {
    float sc[8], bal[8];
#pragma unroll
    for (int j = 0; j < 8; ++j) {
      const float s = 1.f / (1.f + expf(-acc[i][j]));
      sc[j]  = s;
      bal[j] = s + biasr[j];
    }

    float myw[TOPK];
    int   myid[TOPK];
    float prev = 0.f;
    int   flagged = 0;
#pragma unroll
    for (int r = 0; r < TOPK + 1; ++r) {
      float bv = bal[0];
      int   bi = tx * 4;
#pragma unroll
      for (int j = 1; j < 8; ++j) {
        const int ej = (j < 4) ? (tx * 4 + j) : (64 + tx * 4 + (j - 4));
        if (bal[j] > bv) { bv = bal[j]; bi = ej; }
      }
#pragma unroll
      for (int m = 1; m <= 8; m <<= 1) {
        const float ov = __shfl_xor(bv, m);
        const int   oi = __shfl_xor(bi, m);
        if (ov > bv || (ov == bv && oi < bi)) { bv = ov; bi = oi; }
      }
      if (r > 0 && (prev - bv) < MARGIN) flagged = 1;
      prev = bv;
      if (r < TOPK) {
        const int ls = (bi < 64) ? (bi >> 2) : ((bi - 64) >> 2);
        const int jt = (bi < 64) ? (bi & 3) : (4 + ((bi - 64) & 3));
        const float a0 = (jt & 1) ? sc[1] : sc[0];
        const float a1 = (jt & 1) ? sc[3] : sc[2];
        const float a2 = (jt & 1) ? sc[5] : sc[4];
        const float a3 = (jt & 1) ? sc[7] : sc[6];
        const float b0 = (jt & 2) ? a1 : a0;
        const float b1 = (jt & 2) ? a3 : a2;
        const float sv = (jt & 4) ? b1 : b0;
        const float sw = __shfl(sv, gbase | ls);
        myw[r]  = sw;
        myid[r] = bi;
#pragma unroll
        for (int j = 0; j < 8; ++j)
          if (tx == ls && j == jt) bal[j] = -INFINITY;
      }
    }

    if (tx == 0) {
      float den = 0.f;
#pragma unroll
      for (int r = 0; r < TOPK; ++r) den += fabsf(myw[r]);
      den = fmaxf(den, 1e-12f);
      const int t = t0 + ty * 4 + i;
      float4* wo = (float4*)(out_w + (size_t)t * TOPK);
      float4* io = (float4*)(out_i + (size_t)t * TOPK);
      wo[0] = make_float4(myw[0] / den, myw[1] / den, myw[2] / den, myw[3] / den);
      wo[1] = make_float4(myw[4] / den, myw[5] / den, myw[6] / den, myw[7] / den);
      io[0] = make_float4((float)myid[0], (float)myid[1], (float)myid[2], (float)myid[3]);
      io[1] = make_float4((float)myid[4], (float)myid[5], (float)myid[6], (float)myid[7]);
      if (flagged) atomicOr(&mask[t >> 5], 1u << (t & 31));
    }
  }
}

// ---------------- Compaction: bitmask -> ordered token list (deterministic) ----------------
__global__ __launch_bounds__(1024) void router_compact(
    const unsigned int* __restrict__ mask, int* __restrict__ cnt,
    int* __restrict__ flags, int nwords) {
  __shared__ int wsum[17];
  const int tid = threadIdx.x;
  unsigned int w = (tid < nwords) ? mask[tid] : 0u;
  const int c = __popc(w);
  const int lane = tid & 63;
  const int wv   = tid >> 6;
  int inc = c;
#pragma unroll
  for (int m = 1; m < 64; m <<= 1) {
    const int v = __shfl_up(inc, m);
    if (lane >= m) inc += v;
  }
  if (lane == 63) wsum[wv + 1] = inc;
  __syncthreads();
  if (tid == 0) {
    wsum[0] = 0;
    for (int i = 1; i <= 16; ++i) wsum[i] += wsum[i - 1];
    cnt[0] = wsum[16];
  }
  __syncthreads();
  int off = wsum[wv] + inc - c;
  while (w) {
    const int b = __ffs(w) - 1;
    w &= w - 1u;
    flags[off++] = tid * 32 + b;
  }
}

// ---------------- Pass 2: fp64 recompute, 4 tokens per block (grid-stride) ----------------
__global__ __launch_bounds__(256) void router_pass2(
    const float* __restrict__ x, const float* __restrict__ W,
    const float* __restrict__ bias,
    float* __restrict__ out_w, float* __restrict__ out_i,
    const int* __restrict__ cnt, const int* __restrict__ flags, int H) {
  __shared__ float  xs[4 * 4096];      // 64 KB (H == 4096)
  __shared__ double red[4 * NE];       // 4 KB

  const int tid = threadIdx.x;
  const int e   = tid & 127;
  const int h   = tid >> 7;            // K-half
  const int count = cnt[0];

  for (int g = blockIdx.x; g * 4 < count; g += gridDim.x) {
    const int nt = min(4, count - g * 4);
    int toks[4];
#pragma unroll
    for (int t = 0; t < 4; ++t) toks[t] = flags[g * 4 + min(t, nt - 1)];

    __syncthreads();                   // protect xs/red reuse across iterations
#pragma unroll
    for (int t = 0; t < 4; ++t) {
      const float* xp = x + (size_t)toks[t] * H;
#pragma unroll
      for (int c = 0; c < 4; ++c) {
        const int fi = (c * 256 + tid) * 4;
        *(float4*)(xs + t * 4096 + fi) = *(const float4*)(xp + fi);
      }
    }
    __syncthreads();

    double a[4] = {0.0, 0.0, 0.0, 0.0};
    {
      const float* wp = W + (size_t)e * H + h * 2048;
      const float* xb = xs + h * 2048;
      for (int kk = 0; kk < 2048; kk += 4) {
        const float4 wv = *(const float4*)(wp + kk);
#pragma unroll
        for (int t = 0; t < 4; ++t) {
          const float4 xv = *(const float4*)(xb + t * 4096 + kk);
          a[t] = fma((double)xv.x, (double)wv.x, a[t]);
          a[t] = fma((double)xv.y, (double)wv.y, a[t]);
          a[t] = fma((double)xv.z, (double)wv.z, a[t]);
          a[t] = fma((double)xv.w, (double)wv.w, a[t]);
        }
      }
    }

    if (h == 1) {
#pragma unroll
      for (int t = 0; t < 4; ++t) red[t * NE + e] = a[t];
    }
    __syncthreads();
    if (h == 0) {
#pragma unroll
      for (int t = 0; t < 4; ++t)
        red[t * NE + e] = 1.0 / (1.0 + exp(-(a[t] + red[t * NE + e])));
    }
    __syncthreads();

    if (tid < 64) {
      const int l = tid;
      const double b0d = (double)bias[l];
      const double b1d = (double)bias[64 + l];
#pragma unroll
      for (int t = 0; t < 4; ++t) {
        const double s0 = red[t * NE + l];
        const double s1 = red[t * NE + 64 + l];
        double g0 = s0 + b0d;
        double g1 = s1 + b1d;
        double myw[TOPK]; int myid[TOPK];
#pragma unroll
        for (int r = 0; r < TOPK; ++r) {
          double bv; int bi;
          if (g1 > g0) { bv = g1; bi = 64 + l; } else { bv = g0; bi = l; }
#pragma unroll
          for (int m = 1; m <= 32; m <<= 1) {
            const double ov = __shfl_xor(bv, m);
            const int    oi = __shfl_xor(bi, m);
            if (ov > bv || (ov == bv && oi < bi)) { bv = ov; bi = oi; }
          }
          const int ls   = bi & 63;
          const int slot = bi >> 6;
          const double sv = slot ? s1 : s0;
          const double sw = __shfl(sv, ls);
          myw[r]  = sw;
          myid[r] = bi;
          if (l == ls) { if (slot) g1 = -INFINITY; else g0 = -INFINITY; }
        }
        if (l == 0 && t < nt) {
          double den = 0.0;
#pragma unroll
          for (int r = 0; r < TOPK; ++r) den += fabs(myw[r]);
          den = fmax(den, 1e-12);
          const int tok = toks[t];
#pragma unroll
          for (int r = 0; r < TOPK; ++r) {
            out_w[(size_t)tok * TOPK + r] = (float)(myw[r] / den);
            out_i[(size_t)tok * TOPK + r] = (float)myid[r];
          }
        }
      }
    }
  }
}

extern "C" void kernel_launch(void* const* d_in, const int* in_sizes, int n_in,
                              void* d_out, int out_size, void* d_ws, size_t ws_size,
                              hipStream_t stream) {
  const float* x    = (const float*)d_in[0];
  const float* W    = (const float*)d_in[1];
  const float* bias = (const float*)d_in[2];
  const int E = in_sizes[2];            // 128
  const int H = in_sizes[1] / E;        // 4096
  const int T = in_sizes[0] / H;        // 32768
  (void)E; (void)n_in; (void)ws_size; (void)out_size;

  float* out_w = (float*)d_out;
  float* out_i = out_w + (size_t)T * TOPK;

  const int nwords = (T + 31) / 32;     // 1024
  unsigned int* mask = (unsigned int*)d_ws;              // 4 KB
  int* cnt   = (int*)d_ws + nwords;
  int* flags = (int*)d_ws + nwords + 4;

  hipMemsetAsync(d_ws, 0, (size_t)(nwords + 4) * 4, stream);
  router_pass1<<<dim3(T / BT), dim3(256), 0, stream>>>(x, W, bias, out_w, out_i, mask, T, H);
  router_compact<<<dim3(1), dim3(1024), 0, stream>>>(mask, cnt, flags, nwords);
  router_pass2<<<dim3(2048), dim3(256), 0, stream>>>(x, W, bias, out_w, out_i, cnt, flags, H);
}